// Round 8
// baseline (489.677 us; speedup 1.0000x reference)
//
#include <hip/hip_runtime.h>
#include <cstdint>
#include <cstddef>

// Causal self-attention. fp32 in / fp32 out. bf16 MFMA compute, fp32 accum.
// B=4 T=1024 C=2048 H=16 Dh=128.
//
// R16: GEMM frozen at R14 (129us, best of 5 schedule variants; R15 reg-dbuf
// regressed 129->143 -> reverted). transpose_w = R12 scalar (R15 A/B: ~7us
// better than vectorized). NEW: attention T14 async-STAGE split -- issue
// next K/V tile's global loads into REGISTERS right after the publish
// barrier (HBM latency hides under QK^T/softmax/PV), ds_write them at next
// iter top. Replaces per-iter {async16 -> syncthreads vmcnt(0) drain}.
// Zero extra LDS (occupancy stays 3 blocks/CU; avoids m132 trap); +32 VGPR
// static-indexed (rule 20); ds_write addr == async16's base+lane*16 layout
// so the proven XOR-swizzle read side is untouched. WAR on kreg/vreg is
// compiler-visible; writes protected by prev iter's trailing barrier.

typedef __attribute__((ext_vector_type(8))) __bf16 bf16x8;
typedef __attribute__((ext_vector_type(4))) float f32x4;
typedef unsigned short u16;

#define NEG_BIG (-1.0e30f)

__device__ __forceinline__ u16 f2bf(float f) {
    union { float f; uint32_t u; } v; v.f = f;
    uint32_t r = v.u + 0x7FFFu + ((v.u >> 16) & 1u);   // RNE
    return (u16)(r >> 16);
}

__device__ __forceinline__ uint32_t pack2(float a, float b) {
    return (uint32_t)f2bf(a) | ((uint32_t)f2bf(b) << 16);
}

__device__ __forceinline__ f32x4 mfma16(bf16x8 a, bf16x8 b, f32x4 c) {
    return __builtin_amdgcn_mfma_f32_16x16x32_bf16(a, b, c, 0, 0, 0);
}

// async global->LDS, 16B/lane; LDS dst = wave-uniform base (+lane*16 by HW)
__device__ __forceinline__ void async16(const u16* g, u16* l) {
    __builtin_amdgcn_global_load_lds(
        (const __attribute__((address_space(1))) void*)g,
        (__attribute__((address_space(3))) void*)l, 16, 0, 0);
}

// ---------------------------------------------------------------------------
__global__ __launch_bounds__(256) void cvt_bf16(
    const float* __restrict__ x, u16* __restrict__ xb) {
    size_t i = ((size_t)blockIdx.x * 256 + threadIdx.x) * 8;
    float4 u = *(const float4*)(x + i);
    float4 v = *(const float4*)(x + i + 4);
    uint4 p;
    p.x = pack2(u.x, u.y); p.y = pack2(u.z, u.w);
    p.z = pack2(v.x, v.y); p.w = pack2(v.z, v.w);
    *(uint4*)(xb + i) = p;
}

// ---------------------------------------------------------------------------
// R12-proven scalar transpose.
// ---------------------------------------------------------------------------
__global__ __launch_bounds__(256) void transpose_w(
    const float* __restrict__ W, int ldW, u16* __restrict__ WT) {
    __shared__ u16 tile[64][68];
    const int n0 = blockIdx.x * 64, k0 = blockIdx.y * 64;
    const int t = threadIdx.x;
    for (int i = t; i < 4096; i += 256) {
        int r = i >> 6, c = i & 63;
        tile[r][c] = f2bf(W[(size_t)(k0 + r) * ldW + n0 + c]);
    }
    __syncthreads();
    for (int i = t; i < 4096; i += 256) {
        int r = i >> 6, c = i & 63;
        WT[(size_t)(n0 + r) * 2048 + k0 + c] = tile[c][r];
    }
}

// ---------------------------------------------------------------------------
// 128x128 GEMM (R6-proven): used for proj (512 blocks, good occupancy) and
// the fallback path.
// ---------------------------------------------------------------------------
__global__ __launch_bounds__(256) void gemm_k(
    const void* __restrict__ Av, const u16* __restrict__ Bt,
    int N, int amode, int omode,
    float* __restrict__ outf, u16* __restrict__ Qo, u16* __restrict__ Ko,
    u16* __restrict__ Vt) {
    const int K = 2048;
    __shared__ u16 As[128][32];
    __shared__ u16 Bs[128][32];

    const float* A32 = (const float*)Av;
    const u16*   A16 = (const u16*)Av;

    const int m0 = blockIdx.y * 128, n0 = blockIdx.x * 128;
    const int t = threadIdx.x;
    const int w = t >> 6, lane = t & 63;
    const int col = lane & 15, quad = lane >> 4;
    const int wrow = (w >> 1) * 64, wcol = (w & 1) * 64;

    f32x4 acc[4][4];
    #pragma unroll
    for (int i = 0; i < 4; ++i)
        #pragma unroll
        for (int j = 0; j < 4; ++j)
            acc[i][j] = (f32x4){0.f, 0.f, 0.f, 0.f};

    u16* as_flat = &As[0][0];
    u16* bs_flat = &Bs[0][0];
    const int c1 = (w << 6) | lane;
    const int c2 = c1 + 256;

    for (int k0 = 0; k0 < K; k0 += 32) {
        {
            const u16* g1 = Bt + (size_t)(n0 + (c1 >> 2)) * K + k0 + ((c1 & 3) << 3);
            async16(g1, bs_flat + (size_t)w * 512);
            const u16* g2 = Bt + (size_t)(n0 + (c2 >> 2)) * K + k0 + ((c2 & 3) << 3);
            async16(g2, bs_flat + 2048 + (size_t)w * 512);
        }
        if (amode == 2) {
            const u16* g1 = A16 + (size_t)(m0 + (c1 >> 2)) * K + k0 + ((c1 & 3) << 3);
            async16(g1, as_flat + (size_t)w * 512);
            const u16* g2 = A16 + (size_t)(m0 + (c2 >> 2)) * K + k0 + ((c2 & 3) << 3);
            async16(g2, as_flat + 2048 + (size_t)w * 512);
        } else if (amode == 1) {
            #pragma unroll
            for (int cc = 0; cc < 2; ++cc) {
                int c = cc ? c2 : c1;
                int r = c >> 2, ko = (c & 3) << 3;
                int kg = k0 + ko, h = kg >> 7, d = kg & 127;
                int m = m0 + r, b = m >> 10, tt = m & 1023;
                const u16* g = A16 + (((size_t)(b * 16 + h)) * 1024 + tt) * 128 + d;
                async16(g, as_flat + (size_t)(cc ? 2048 : 0) + (size_t)w * 512);
            }
        } else if (amode == 0) {
            #pragma unroll
            for (int c = t; c < 512; c += 256) {
                int r = c >> 2, ko = (c & 3) * 8;
                size_t off = (size_t)(m0 + r) * K + k0 + ko;
                float4 u = *(const float4*)(A32 + off);
                float4 v = *(const float4*)(A32 + off + 4);
                uint4 p;
                p.x = pack2(u.x, u.y); p.y = pack2(u.z, u.w);
                p.z = pack2(v.x, v.y); p.w = pack2(v.z, v.w);
                *(uint4*)&As[r][ko] = p;
            }
        } else {
            #pragma unroll
            for (int c = t; c < 512; c += 256) {
                int r = c >> 2, ko = (c & 3) * 8;
                int kg = k0 + ko, h = kg >> 7, d = kg & 127;
                int m = m0 + r, b = m >> 10, tt = m & 1023;
                *(uint4*)&As[r][ko] =
                    *(const uint4*)(A16 + (((size_t)(b * 16 + h)) * 1024 + tt) * 128 + d);
            }
        }
        __syncthreads();

        bf16x8 afr[4], bfr[4];
        #pragma unroll
        for (int i = 0; i < 4; ++i)
            afr[i] = *(const bf16x8*)&As[wrow + i * 16 + col][quad * 8];
        #pragma unroll
        for (int i = 0; i < 4; ++i)
            bfr[i] = *(const bf16x8*)&Bs[wcol + i * 16 + col][quad * 8];

        #pragma unroll
        for (int mt = 0; mt < 4; ++mt)
            #pragma unroll
            for (int nt = 0; nt < 4; ++nt)
                acc[mt][nt] = mfma16(afr[mt], bfr[nt], acc[mt][nt]);
        __syncthreads();
    }

    #pragma unroll
    for (int mt = 0; mt < 4; ++mt) {
        #pragma unroll
        for (int nt = 0; nt < 4; ++nt) {
            #pragma unroll
            for (int r = 0; r < 4; ++r) {
                int gm = m0 + wrow + mt * 16 + quad * 4 + r;
                int gn = n0 + wcol + nt * 16 + col;
                if (omode == 0) {
                    outf[(size_t)gm * N + gn] = acc[mt][nt][r];
                } else {
                    u16 bv = f2bf(acc[mt][nt][r]);
                    int b = gm >> 10, tq = gm & 1023;
                    if (omode == 3) {
                        int which = gn >> 11, rem = gn & 2047;
                        int h = rem >> 7, d = rem & 127;
                        size_t bh = (size_t)b * 16 + h;
                        if (which == 0)      Qo[(bh * 1024 + tq) * 128 + d] = bv;
                        else if (which == 1) Ko[(bh * 1024 + tq) * 128 + d] = bv;
                        else                 Vt[(bh * 128 + d) * 1024 + tq] = bv;
                    } else {
                        int h = gn >> 7, d = gn & 127;
                        size_t bh = (size_t)b * 16 + h;
                        if (omode == 1) Qo[(bh * 1024 + tq) * 128 + d] = bv;
                        else            Vt[(bh * 128 + d) * 1024 + tq] = bv;
                    }
                }
            }
        }
    }
}

// ---------------------------------------------------------------------------
// R14 gemm192 (proven best, verbatim semantics): 256x192 tile, grid (32,16)
// = 512 blocks = 2 exact rounds. 512 threads = 8 waves (2 wr x 4 wc),
// per-wave 128x48 out, BK=64, 2 fat phases/K-tile. LDS 112KB dbuf.
// Ledger: F1-top vmcnt(2) retires {b*,q0,q1}(cur); F2-top vmcnt(3) retires
// {q2,q3}(cur); outstanding 7->2->5->3->7; never drains to 0.
// ---------------------------------------------------------------------------
__device__ __forceinline__ bf16x8 ldsfrag(const u16* buf, int row, int ksl, int quad) {
    return *(const bf16x8*)(buf + (size_t)row * 64 +
                            ((((ksl << 2) | quad) ^ (row & 7)) << 3));
}

// stage one 64-row x 64-k chunk; src row-major with leading dim 2048
__device__ __forceinline__ void stage64(
    u16* dst, const u16* src, int row0, int k0, int w, int lane) {
    int s = (w << 6) | lane;
    int r = s >> 3;                       // 0..63
    int gc = (s & 7) ^ (r & 7);           // inverse swizzle on global chunk
    async16(src + (size_t)(row0 + r) * 2048 + k0 + (gc << 3),
            dst + ((size_t)(w << 6)) * 8);
}

__global__ __launch_bounds__(512, 2) void gemm192(
    const u16* __restrict__ A, const u16* __restrict__ Bt,
    u16* __restrict__ Qo, u16* __restrict__ Ko, u16* __restrict__ Vt) {
    __shared__ u16 As[2][256 * 64];
    __shared__ u16 Bs[2][192 * 64];

    const int m0 = blockIdx.y * 256, n0 = blockIdx.x * 192;
    const int t = threadIdx.x;
    const int w = t >> 6, lane = t & 63;
    const int col = lane & 15, quad = lane >> 4;
    const int wr16 = ((w >> 2) & 1) << 4;   // 0 or 16
    const int wc48 = (w & 3) * 48;          // 0,48,96,144

    f32x4 acc[8][3];
    #pragma unroll
    for (int i = 0; i < 8; ++i)
        #pragma unroll
        for (int j = 0; j < 3; ++j)
            acc[i][j] = (f32x4){0.f, 0.f, 0.f, 0.f};

    // prologue, ledger issue order: b0,b1,b2,q0,q1,q2,q3 (kt 0 -> buf 0)
    stage64(Bs[0] + 0 * 4096,  Bt, n0 + 0,   0, w, lane);   // b0
    stage64(Bs[0] + 1 * 4096,  Bt, n0 + 64,  0, w, lane);   // b1
    stage64(Bs[0] + 2 * 4096,  Bt, n0 + 128, 0, w, lane);   // b2
    stage64(As[0] + 0 * 4096,  A,  m0 + 0,   0, w, lane);   // q0
    stage64(As[0] + 1 * 4096,  A,  m0 + 64,  0, w, lane);   // q1
    stage64(As[0] + 2 * 4096,  A,  m0 + 128, 0, w, lane);   // q2
    stage64(As[0] + 3 * 4096,  A,  m0 + 192, 0, w, lane);   // q3

    bf16x8 af[8], bfc[6];
    const int NT = 32;   // 2048 / 64

    for (int kt = 0; kt < NT; ++kt) {
        const int cur = kt & 1, nxt = cur ^ 1;
        const int kN = ((kt + 1) & 31) * 64;   // wrap at tail: redundant, safe

        // ---- F1: vmcnt(2) retires {b0,b1,b2,q0,q1}(cur); barrier publishes
        //      across waves; read a(mh0)+b(all); stage b*(next); MFMA mh0.
        asm volatile("s_waitcnt vmcnt(2)" ::: "memory");
        __builtin_amdgcn_s_barrier();
        #pragma unroll
        for (int mr = 0; mr < 4; ++mr)
            #pragma unroll
            for (int ks = 0; ks < 2; ++ks)
                af[mr * 2 + ks] = ldsfrag(As[cur], mr * 32 + wr16 + col, ks, quad);
        #pragma unroll
        for (int nt = 0; nt < 3; ++nt)
            #pragma unroll
            for (int ks = 0; ks < 2; ++ks)
                bfc[nt * 2 + ks] = ldsfrag(Bs[cur], wc48 + nt * 16 + col, ks, quad);
        stage64(Bs[nxt] + 0 * 4096, Bt, n0 + 0,   kN, w, lane);
        stage64(Bs[nxt] + 1 * 4096, Bt, n0 + 64,  kN, w, lane);
        stage64(Bs[nxt] + 2 * 4096, Bt, n0 + 128, kN, w, lane);
        __builtin_amdgcn_s_setprio(1);
        #pragma unroll
        for (int mr = 0; mr < 4; ++mr)
            #pragma unroll
            for (int nt = 0; nt < 3; ++nt)
                #pragma unroll
                for (int ks = 0; ks < 2; ++ks)
                    acc[mr][nt] = mfma16(af[mr * 2 + ks], bfc[nt * 2 + ks], acc[mr][nt]);
        __builtin_amdgcn_s_setprio(0);

        // ---- F2: vmcnt(3) retires {q2,q3}(cur); barrier; read a(mh1);
        //      stage q*(next); MFMA mh1 (b-frags reused from regs).
        asm volatile("s_waitcnt vmcnt(3)" ::: "memory");
        __builtin_amdgcn_s_barrier();
        #pragma unroll
        for (int mr = 0; mr < 4; ++mr)
            #pragma unroll
            for (int ks = 0; ks < 2; ++ks)
                af[mr * 2 + ks] = ldsfrag(As[cur], (mr + 4) * 32 + wr16 + col, ks, quad);
        stage64(As[nxt] + 0 * 4096, A, m0 + 0,   kN, w, lane);
        stage64(As[nxt] + 1 * 4096, A, m0 + 64,  kN, w, lane);
        stage64(As[nxt] + 2 * 4096, A, m0 + 128, kN, w, lane);
        stage64(As[nxt] + 3 * 4096, A, m0 + 192, kN, w, lane);
        __builtin_amdgcn_s_setprio(1);
        #pragma unroll
        for (int mr = 0; mr < 4; ++mr)
            #pragma unroll
            for (int nt = 0; nt < 3; ++nt)
                #pragma unroll
                for (int ks = 0; ks < 2; ++ks)
                    acc[mr + 4][nt] = mfma16(af[mr * 2 + ks], bfc[nt * 2 + ks], acc[mr + 4][nt]);
        __builtin_amdgcn_s_setprio(0);
    }

    // ---- epilogue: QKV scatter (same lane->element mapping as gemm_k)
    #pragma unroll
    for (int mr = 0; mr < 8; ++mr) {
        #pragma unroll
        for (int nt = 0; nt < 3; ++nt) {
            #pragma unroll
            for (int r = 0; r < 4; ++r) {
                int gm = m0 + mr * 32 + wr16 + quad * 4 + r;
                int gn = n0 + wc48 + nt * 16 + col;
                u16 bv = f2bf(acc[mr][nt][r]);
                int b = gm >> 10, tq = gm & 1023;
                int which = gn >> 11, rem = gn & 2047;
                int hh = rem >> 7, d = rem & 127;
                size_t bh = (size_t)b * 16 + hh;
                if (which == 0)      Qo[(bh * 1024 + tq) * 128 + d] = bv;
                else if (which == 1) Ko[(bh * 1024 + tq) * 128 + d] = bv;
                else                 Vt[(bh * 128 + d) * 1024 + tq] = bv;
            }
        }
    }
}

// ---------------------------------------------------------------------------
// Flash attention R16: R8 structure + T14 async-STAGE split (reg staging).
// Grid (T/64, H, B), 256 threads = 4 waves, 16 q/wave. Per iter:
//   ds_write staged regs (kt) -> barrier -> issue global loads (kt+1) ->
//   QK^T / softmax / PV -> barrier.
// LDS unchanged (41.5KB, 3 blocks/CU). ds_write addr replicates async16's
// base+lane*16 linear layout; XOR-swizzle read side untouched.
// ---------------------------------------------------------------------------
__global__ __launch_bounds__(256) void attn_kernel(
    u16* __restrict__ Q, const u16* __restrict__ K,
    const u16* __restrict__ VT) {
    __shared__ u16 Ks[64 * 128];     // swizzled, unpadded
    __shared__ u16 Vs[128 * 64];     // swizzled, unpadded
    __shared__ u16 Ps[4][16][68];    // wave-private, padded

    const int qb = (int)(gridDim.x - 1) - (int)blockIdx.x;   // heavy first
    const int h = blockIdx.y, b = blockIdx.z;
    const int t = threadIdx.x;
    const int w = t >> 6, lane = t & 63;
    const int col = lane & 15, quad = lane >> 4;
    const int sw = col & 7;                       // read-side swizzle key
    const size_t bh = (size_t)b * 16 + h;
    u16* Qb = Q + bh * (1024 * 128);
    const u16* Kb = K + bh * (1024 * 128);
    const u16* Vb = VT + bh * (128 * 1024);
    const int q_lane = qb * 64 + w * 16 + col;
    const int s0 = w * 64 + lane;                 // base chunk slot

    // Q fragment, B-operand: lane holds Q[q=col][dh=kq*32+quad*8+j]
    bf16x8 qf[4];
    {
        const u16* qp = Qb + (size_t)q_lane * 128 + quad * 8;
        #pragma unroll
        for (int kq = 0; kq < 4; ++kq)
            qf[kq] = *(const bf16x8*)(qp + kq * 32);
    }

    f32x4 o[8];
    #pragma unroll
    for (int i = 0; i < 8; ++i) o[i] = (f32x4){0.f, 0.f, 0.f, 0.f};
    float m = NEG_BIG, l = 0.f;
    const float scale = 0.08838834764831845f;  // 1/sqrt(128)

    // ---- prologue: load tile kt=0 into regs (swizzled global src) ----
    uint4 kreg[4], vreg[4];
    #pragma unroll
    for (int i = 0; i < 4; ++i) {
        int s = i * 256 + s0;
        int kr = s >> 4, kc = s & 15;             // K: 16 chunks/row
        kreg[i] = *(const uint4*)(Kb + (size_t)kr * 128 + ((kc ^ (kr & 7)) << 3));
        int vr = s >> 3, vc = s & 7;              // V: 8 chunks/row
        vreg[i] = *(const uint4*)(Vb + (size_t)vr * 1024 + ((vc ^ (vr & 7)) << 3));
    }

    for (int kt = 0; kt <= qb; ++kt) {
        // ---- write staged regs (tile kt) to LDS; data-dep waits vmcnt ----
        #pragma unroll
        for (int i = 0; i < 4; ++i) {
            int s = i * 256 + s0;
            *(uint4*)(Ks + (size_t)s * 8) = kreg[i];
            *(uint4*)(Vs + (size_t)s * 8) = vreg[i];
        }
        __syncthreads();   // publish LDS (also protects Ps reuse)

        // ---- issue next tile's loads; latency hides under compute ----
        if (kt < qb) {
            const u16* Kt = Kb + (size_t)(kt + 1) * (64 * 128);
            const int kvoff = (kt + 1) * 64;
            #pragma unroll
            for (int i = 0; i < 4; ++i) {
                int s = i * 256 + s0;
                int kr = s >> 4, kc = s & 15;
                kreg[i] = *(const uint4*)(Kt + (size_t)kr * 128 + ((kc ^ (kr & 7)) << 3));
                int vr = s >> 3, vc = s & 7;
                vreg[i] = *(const uint4*)(Vb + (size_t)vr * 1024 + kvoff + ((vc ^ (vr & 7)) << 3));
            }
        }

        // ---- S^T = K.Q^T ----
        const bool need_mask = (kt == qb);
        const int ttmax = need_mask ? w : 3;          // skip fully-masked strips
        f32x4 s[4];
        #pragma unroll
        for (int tt = 0; tt < 4; ++tt) {
            if (tt > ttmax) { s[tt] = (f32x4){NEG_BIG, NEG_BIG, NEG_BIG, NEG_BIG}; continue; }
            const u16* kbase = Ks + (size_t)(tt * 16 + col) * 128;
            f32x4 a = (f32x4){0.f, 0.f, 0.f, 0.f};
            #pragma unroll
            for (int kq = 0; kq < 4; ++kq)
                a = mfma16(*(const bf16x8*)(kbase + (((kq * 4 + quad) ^ sw) << 3)),
                           qf[kq], a);
            s[tt] = a;
        }

        // ---- scale + mask + max ----
        float rmax = NEG_BIG;
        #pragma unroll
        for (int tt = 0; tt < 4; ++tt) {
            if (tt > ttmax) continue;
            #pragma unroll
            for (int r = 0; r < 4; ++r) {
                float v = s[tt][r] * scale;
                int tg = kt * 64 + tt * 16 + quad * 4 + r;
                if (need_mask && tg > q_lane) v = NEG_BIG;
                s[tt][r] = v;
                rmax = fmaxf(rmax, v);
            }
        }
        rmax = fmaxf(rmax, __shfl_xor(rmax, 16, 64));
        rmax = fmaxf(rmax, __shfl_xor(rmax, 32, 64));

        float mnew = fmaxf(m, rmax);
        float alpha = __expf(m - mnew);
        m = mnew;

        // ---- P = exp(S^T - m) -> Ps[w][q][t] ----
        float rsum = 0.f;
        #pragma unroll
        for (int tt = 0; tt < 4; ++tt) {
            uint32_t* dst = (uint32_t*)&Ps[w][col][tt * 16 + quad * 4];
            if (tt > ttmax) { dst[0] = 0u; dst[1] = 0u; continue; }
            float p0 = __expf(s[tt][0] - mnew);
            float p1 = __expf(s[tt][1] - mnew);
            float p2 = __expf(s[tt][2] - mnew);
            float p3 = __expf(s[tt][3] - mnew);
            rsum += (p0 + p1) + (p2 + p3);
            dst[0] = pack2(p0, p1);
            dst[1] = pack2(p2, p3);
        }
        rsum += __shfl_xor(rsum, 16, 64);
        rsum += __shfl_xor(rsum, 32, 64);
        l = l * alpha + rsum;

        #pragma unroll
        for (int dt = 0; dt < 8; ++dt)
            #pragma unroll
            for (int r = 0; r < 4; ++r) o[dt][r] *= alpha;

        // ---- O^T += V^T.P^T ----
        #pragma unroll
        for (int ks = 0; ks < 2; ++ks) {
            bf16x8 pf = *(const bf16x8*)&Ps[w][col][ks * 32 + quad * 8];
            #pragma unroll
            for (int dt = 0; dt < 8; ++dt) {
                const u16* vbase = Vs + (size_t)(dt * 16 + col) * 64;
                o[dt] = mfma16(*(const bf16x8*)(vbase + (((ks * 4 + quad) ^ sw) << 3)),
                               pf, o[dt]);
            }
        }
        __syncthreads();   // all waves done reading before next overwrite
    }

    // epilogue: lane holds O^T[d=dt*16+quad*4+r][q=col]; 8B packed stores
    float inv = 1.0f / l;
    #pragma unroll
    for (int dt = 0; dt < 8; ++dt) {
        uint2 p;
        p.x = pack2(o[dt][0] * inv, o[dt][1] * inv);
        p.y = pack2(o[dt][2] * inv, o[dt][3] * inv);
        *(uint2*)&Qb[(size_t)q_lane * 128 + dt * 16 + quad * 4] = p;
    }
}

// ---------------------------------------------------------------------------
extern "C" void kernel_launch(void* const* d_in, const int* in_sizes, int n_in,
                              void* d_out, int out_size, void* d_ws, size_t ws_size,
                              hipStream_t stream) {
    const float* x      = (const float*)d_in[0];   // [4096, 2048]
    const float* w_qkv  = (const float*)d_in[1];   // [2048, 6144]
    const float* w_proj = (const float*)d_in[2];   // [2048, 2048]
    float* out = (float*)d_out;                    // [4096, 2048]

    const size_t SEG = (size_t)4 * 16 * 1024 * 128;      // 8,388,608 elems
    const size_t NEED_FAST = ((size_t)6144 * 2048 + SEG * 4) * 2;  // 92.3 MB

    if (ws_size >= NEED_FAST + (1u << 20)) {
        u16* wT = (u16*)d_ws;                 // 6144*2048, reused for proj
        u16* xb = wT + (size_t)6144 * 2048;
        u16* Qb = xb + SEG;
        u16* Kb = Qb + SEG;
        u16* Vb = Kb + SEG;

        cvt_bf16<<<4096, 256, 0, stream>>>(x, xb);
        transpose_w<<<dim3(96, 32), 256, 0, stream>>>(w_qkv, 6144, wT);

        gemm192<<<dim3(32, 16), 512, 0, stream>>>(xb, wT, Qb, Kb, Vb);

        attn_kernel<<<dim3(16, 16, 4), 256, 0, stream>>>(Qb, Kb, Vb);

        transpose_w<<<dim3(32, 32), 256, 0, stream>>>(w_proj, 2048, wT);
        gemm_k<<<dim3(16, 32), 256, 0, stream>>>(Qb, wT, 2048, 1, 0,
                                                 out, nullptr, nullptr, nullptr);
    } else {
        // fallback (ws >= 58.7 MB), R5-proven sequence
        u16* wT = (u16*)d_ws;
        u16* Qb = wT + (size_t)2048 * 2048;
        u16* Kb = Qb + SEG;
        u16* Vb = Kb + SEG;

        transpose_w<<<dim3(32, 32), 256, 0, stream>>>(w_qkv + 0, 6144, wT);
        gemm_k<<<dim3(16, 32), 256, 0, stream>>>(x, wT, 2048, 0, 1,
                                                 nullptr, Qb, nullptr, nullptr);
        transpose_w<<<dim3(32, 32), 256, 0, stream>>>(w_qkv + 2048, 6144, wT);
        gemm_k<<<dim3(16, 32), 256, 0, stream>>>(x, wT, 2048, 0, 1,
                                                 nullptr, Kb, nullptr, nullptr);
        transpose_w<<<dim3(32, 32), 256, 0, stream>>>(w_qkv + 4096, 6144, wT);
        gemm_k<<<dim3(16, 32), 256, 0, stream>>>(x, wT, 2048, 0, 2,
                                                 nullptr, nullptr, nullptr, Vb);

        attn_kernel<<<dim3(16, 16, 4), 256, 0, stream>>>(Qb, Kb, Vb);

        transpose_w<<<dim3(32, 32), 256, 0, stream>>>(w_proj, 2048, wT);
        gemm_k<<<dim3(16, 32), 256, 0, stream>>>(Qb, wT, 2048, 3, 0,
                                                 out, nullptr, nullptr, nullptr);
    }
}

// Round 9
// 372.575 us; speedup vs baseline: 1.3143x; 1.3143x over previous
//
#include <hip/hip_runtime.h>
#include <cstdint>
#include <cstddef>

// Causal self-attention. fp32 in / fp32 out. bf16 MFMA compute, fp32 accum.
// B=4 T=1024 C=2048 H=16 Dh=128.
//
// R17: (a) REVERT attn staging to R8 async16 (global_load_lds). R16's T14
// reg-staging regressed attn to 173us: bank-conflict 0->2.13M (manual
// ds_write_b128 at 16B/lane stride = ~8-way conflict) + scattered uint4
// loads; guide's T14 note says reg-staging is net-negative vs gload_lds.
// (b) NEW: q-tile pairing. R16 counters: attn MfmaUtil 4%, VALU 11%,
// Occupancy 11% = latency-bound + scheduling tail (1024 blocks with work
// 1..16 tiles vs 768 resident slots). Pair (qb, 15-qb) per block -> 512
// uniform blocks x 17 tiles = one clean round, no tail. In-place O<-Q
// stays safe: each q-row read+written by exactly one block, read precedes
// write, pass-B rows untouched by pass A; trailing barrier of pass A's
// last iter protects pass B's first restage.
// GEMMs frozen at R14 (gemm192 129us best-of-6; gemm_k proj; scalar
// transpose_w per R15 A/B).

typedef __attribute__((ext_vector_type(8))) __bf16 bf16x8;
typedef __attribute__((ext_vector_type(4))) float f32x4;
typedef unsigned short u16;

#define NEG_BIG (-1.0e30f)

__device__ __forceinline__ u16 f2bf(float f) {
    union { float f; uint32_t u; } v; v.f = f;
    uint32_t r = v.u + 0x7FFFu + ((v.u >> 16) & 1u);   // RNE
    return (u16)(r >> 16);
}

__device__ __forceinline__ uint32_t pack2(float a, float b) {
    return (uint32_t)f2bf(a) | ((uint32_t)f2bf(b) << 16);
}

__device__ __forceinline__ f32x4 mfma16(bf16x8 a, bf16x8 b, f32x4 c) {
    return __builtin_amdgcn_mfma_f32_16x16x32_bf16(a, b, c, 0, 0, 0);
}

// async global->LDS, 16B/lane; LDS dst = wave-uniform base (+lane*16 by HW)
__device__ __forceinline__ void async16(const u16* g, u16* l) {
    __builtin_amdgcn_global_load_lds(
        (const __attribute__((address_space(1))) void*)g,
        (__attribute__((address_space(3))) void*)l, 16, 0, 0);
}

// ---------------------------------------------------------------------------
__global__ __launch_bounds__(256) void cvt_bf16(
    const float* __restrict__ x, u16* __restrict__ xb) {
    size_t i = ((size_t)blockIdx.x * 256 + threadIdx.x) * 8;
    float4 u = *(const float4*)(x + i);
    float4 v = *(const float4*)(x + i + 4);
    uint4 p;
    p.x = pack2(u.x, u.y); p.y = pack2(u.z, u.w);
    p.z = pack2(v.x, v.y); p.w = pack2(v.z, v.w);
    *(uint4*)(xb + i) = p;
}

// ---------------------------------------------------------------------------
// R12-proven scalar transpose.
// ---------------------------------------------------------------------------
__global__ __launch_bounds__(256) void transpose_w(
    const float* __restrict__ W, int ldW, u16* __restrict__ WT) {
    __shared__ u16 tile[64][68];
    const int n0 = blockIdx.x * 64, k0 = blockIdx.y * 64;
    const int t = threadIdx.x;
    for (int i = t; i < 4096; i += 256) {
        int r = i >> 6, c = i & 63;
        tile[r][c] = f2bf(W[(size_t)(k0 + r) * ldW + n0 + c]);
    }
    __syncthreads();
    for (int i = t; i < 4096; i += 256) {
        int r = i >> 6, c = i & 63;
        WT[(size_t)(n0 + r) * 2048 + k0 + c] = tile[c][r];
    }
}

// ---------------------------------------------------------------------------
// 128x128 GEMM (R6-proven): used for proj (512 blocks, good occupancy) and
// the fallback path.
// ---------------------------------------------------------------------------
__global__ __launch_bounds__(256) void gemm_k(
    const void* __restrict__ Av, const u16* __restrict__ Bt,
    int N, int amode, int omode,
    float* __restrict__ outf, u16* __restrict__ Qo, u16* __restrict__ Ko,
    u16* __restrict__ Vt) {
    const int K = 2048;
    __shared__ u16 As[128][32];
    __shared__ u16 Bs[128][32];

    const float* A32 = (const float*)Av;
    const u16*   A16 = (const u16*)Av;

    const int m0 = blockIdx.y * 128, n0 = blockIdx.x * 128;
    const int t = threadIdx.x;
    const int w = t >> 6, lane = t & 63;
    const int col = lane & 15, quad = lane >> 4;
    const int wrow = (w >> 1) * 64, wcol = (w & 1) * 64;

    f32x4 acc[4][4];
    #pragma unroll
    for (int i = 0; i < 4; ++i)
        #pragma unroll
        for (int j = 0; j < 4; ++j)
            acc[i][j] = (f32x4){0.f, 0.f, 0.f, 0.f};

    u16* as_flat = &As[0][0];
    u16* bs_flat = &Bs[0][0];
    const int c1 = (w << 6) | lane;
    const int c2 = c1 + 256;

    for (int k0 = 0; k0 < K; k0 += 32) {
        {
            const u16* g1 = Bt + (size_t)(n0 + (c1 >> 2)) * K + k0 + ((c1 & 3) << 3);
            async16(g1, bs_flat + (size_t)w * 512);
            const u16* g2 = Bt + (size_t)(n0 + (c2 >> 2)) * K + k0 + ((c2 & 3) << 3);
            async16(g2, bs_flat + 2048 + (size_t)w * 512);
        }
        if (amode == 2) {
            const u16* g1 = A16 + (size_t)(m0 + (c1 >> 2)) * K + k0 + ((c1 & 3) << 3);
            async16(g1, as_flat + (size_t)w * 512);
            const u16* g2 = A16 + (size_t)(m0 + (c2 >> 2)) * K + k0 + ((c2 & 3) << 3);
            async16(g2, as_flat + 2048 + (size_t)w * 512);
        } else if (amode == 1) {
            #pragma unroll
            for (int cc = 0; cc < 2; ++cc) {
                int c = cc ? c2 : c1;
                int r = c >> 2, ko = (c & 3) << 3;
                int kg = k0 + ko, h = kg >> 7, d = kg & 127;
                int m = m0 + r, b = m >> 10, tt = m & 1023;
                const u16* g = A16 + (((size_t)(b * 16 + h)) * 1024 + tt) * 128 + d;
                async16(g, as_flat + (size_t)(cc ? 2048 : 0) + (size_t)w * 512);
            }
        } else if (amode == 0) {
            #pragma unroll
            for (int c = t; c < 512; c += 256) {
                int r = c >> 2, ko = (c & 3) * 8;
                size_t off = (size_t)(m0 + r) * K + k0 + ko;
                float4 u = *(const float4*)(A32 + off);
                float4 v = *(const float4*)(A32 + off + 4);
                uint4 p;
                p.x = pack2(u.x, u.y); p.y = pack2(u.z, u.w);
                p.z = pack2(v.x, v.y); p.w = pack2(v.z, v.w);
                *(uint4*)&As[r][ko] = p;
            }
        } else {
            #pragma unroll
            for (int c = t; c < 512; c += 256) {
                int r = c >> 2, ko = (c & 3) * 8;
                int kg = k0 + ko, h = kg >> 7, d = kg & 127;
                int m = m0 + r, b = m >> 10, tt = m & 1023;
                *(uint4*)&As[r][ko] =
                    *(const uint4*)(A16 + (((size_t)(b * 16 + h)) * 1024 + tt) * 128 + d);
            }
        }
        __syncthreads();

        bf16x8 afr[4], bfr[4];
        #pragma unroll
        for (int i = 0; i < 4; ++i)
            afr[i] = *(const bf16x8*)&As[wrow + i * 16 + col][quad * 8];
        #pragma unroll
        for (int i = 0; i < 4; ++i)
            bfr[i] = *(const bf16x8*)&Bs[wcol + i * 16 + col][quad * 8];

        #pragma unroll
        for (int mt = 0; mt < 4; ++mt)
            #pragma unroll
            for (int nt = 0; nt < 4; ++nt)
                acc[mt][nt] = mfma16(afr[mt], bfr[nt], acc[mt][nt]);
        __syncthreads();
    }

    #pragma unroll
    for (int mt = 0; mt < 4; ++mt) {
        #pragma unroll
        for (int nt = 0; nt < 4; ++nt) {
            #pragma unroll
            for (int r = 0; r < 4; ++r) {
                int gm = m0 + wrow + mt * 16 + quad * 4 + r;
                int gn = n0 + wcol + nt * 16 + col;
                if (omode == 0) {
                    outf[(size_t)gm * N + gn] = acc[mt][nt][r];
                } else {
                    u16 bv = f2bf(acc[mt][nt][r]);
                    int b = gm >> 10, tq = gm & 1023;
                    if (omode == 3) {
                        int which = gn >> 11, rem = gn & 2047;
                        int h = rem >> 7, d = rem & 127;
                        size_t bh = (size_t)b * 16 + h;
                        if (which == 0)      Qo[(bh * 1024 + tq) * 128 + d] = bv;
                        else if (which == 1) Ko[(bh * 1024 + tq) * 128 + d] = bv;
                        else                 Vt[(bh * 128 + d) * 1024 + tq] = bv;
                    } else {
                        int h = gn >> 7, d = gn & 127;
                        size_t bh = (size_t)b * 16 + h;
                        if (omode == 1) Qo[(bh * 1024 + tq) * 128 + d] = bv;
                        else            Vt[(bh * 128 + d) * 1024 + tq] = bv;
                    }
                }
            }
        }
    }
}

// ---------------------------------------------------------------------------
// R14 gemm192 (proven best, frozen): 256x192 tile, grid (32,16) = 512
// blocks = 2 exact rounds. 512 threads = 8 waves (2 wr x 4 wc), per-wave
// 128x48 out, BK=64, 2 fat phases/K-tile. LDS 112KB dbuf.
// Ledger: F1-top vmcnt(2) retires {b*,q0,q1}(cur); F2-top vmcnt(3) retires
// {q2,q3}(cur); outstanding 7->2->5->3->7; never drains to 0.
// ---------------------------------------------------------------------------
__device__ __forceinline__ bf16x8 ldsfrag(const u16* buf, int row, int ksl, int quad) {
    return *(const bf16x8*)(buf + (size_t)row * 64 +
                            ((((ksl << 2) | quad) ^ (row & 7)) << 3));
}

// stage one 64-row x 64-k chunk; src row-major with leading dim 2048
__device__ __forceinline__ void stage64(
    u16* dst, const u16* src, int row0, int k0, int w, int lane) {
    int s = (w << 6) | lane;
    int r = s >> 3;                       // 0..63
    int gc = (s & 7) ^ (r & 7);           // inverse swizzle on global chunk
    async16(src + (size_t)(row0 + r) * 2048 + k0 + (gc << 3),
            dst + ((size_t)(w << 6)) * 8);
}

__global__ __launch_bounds__(512, 2) void gemm192(
    const u16* __restrict__ A, const u16* __restrict__ Bt,
    u16* __restrict__ Qo, u16* __restrict__ Ko, u16* __restrict__ Vt) {
    __shared__ u16 As[2][256 * 64];
    __shared__ u16 Bs[2][192 * 64];

    const int m0 = blockIdx.y * 256, n0 = blockIdx.x * 192;
    const int t = threadIdx.x;
    const int w = t >> 6, lane = t & 63;
    const int col = lane & 15, quad = lane >> 4;
    const int wr16 = ((w >> 2) & 1) << 4;   // 0 or 16
    const int wc48 = (w & 3) * 48;          // 0,48,96,144

    f32x4 acc[8][3];
    #pragma unroll
    for (int i = 0; i < 8; ++i)
        #pragma unroll
        for (int j = 0; j < 3; ++j)
            acc[i][j] = (f32x4){0.f, 0.f, 0.f, 0.f};

    // prologue, ledger issue order: b0,b1,b2,q0,q1,q2,q3 (kt 0 -> buf 0)
    stage64(Bs[0] + 0 * 4096,  Bt, n0 + 0,   0, w, lane);   // b0
    stage64(Bs[0] + 1 * 4096,  Bt, n0 + 64,  0, w, lane);   // b1
    stage64(Bs[0] + 2 * 4096,  Bt, n0 + 128, 0, w, lane);   // b2
    stage64(As[0] + 0 * 4096,  A,  m0 + 0,   0, w, lane);   // q0
    stage64(As[0] + 1 * 4096,  A,  m0 + 64,  0, w, lane);   // q1
    stage64(As[0] + 2 * 4096,  A,  m0 + 128, 0, w, lane);   // q2
    stage64(As[0] + 3 * 4096,  A,  m0 + 192, 0, w, lane);   // q3

    bf16x8 af[8], bfc[6];
    const int NT = 32;   // 2048 / 64

    for (int kt = 0; kt < NT; ++kt) {
        const int cur = kt & 1, nxt = cur ^ 1;
        const int kN = ((kt + 1) & 31) * 64;   // wrap at tail: redundant, safe

        // ---- F1: vmcnt(2) retires {b0,b1,b2,q0,q1}(cur); barrier publishes
        //      across waves; read a(mh0)+b(all); stage b*(next); MFMA mh0.
        asm volatile("s_waitcnt vmcnt(2)" ::: "memory");
        __builtin_amdgcn_s_barrier();
        #pragma unroll
        for (int mr = 0; mr < 4; ++mr)
            #pragma unroll
            for (int ks = 0; ks < 2; ++ks)
                af[mr * 2 + ks] = ldsfrag(As[cur], mr * 32 + wr16 + col, ks, quad);
        #pragma unroll
        for (int nt = 0; nt < 3; ++nt)
            #pragma unroll
            for (int ks = 0; ks < 2; ++ks)
                bfc[nt * 2 + ks] = ldsfrag(Bs[cur], wc48 + nt * 16 + col, ks, quad);
        stage64(Bs[nxt] + 0 * 4096, Bt, n0 + 0,   kN, w, lane);
        stage64(Bs[nxt] + 1 * 4096, Bt, n0 + 64,  kN, w, lane);
        stage64(Bs[nxt] + 2 * 4096, Bt, n0 + 128, kN, w, lane);
        __builtin_amdgcn_s_setprio(1);
        #pragma unroll
        for (int mr = 0; mr < 4; ++mr)
            #pragma unroll
            for (int nt = 0; nt < 3; ++nt)
                #pragma unroll
                for (int ks = 0; ks < 2; ++ks)
                    acc[mr][nt] = mfma16(af[mr * 2 + ks], bfc[nt * 2 + ks], acc[mr][nt]);
        __builtin_amdgcn_s_setprio(0);

        // ---- F2: vmcnt(3) retires {q2,q3}(cur); barrier; read a(mh1);
        //      stage q*(next); MFMA mh1 (b-frags reused from regs).
        asm volatile("s_waitcnt vmcnt(3)" ::: "memory");
        __builtin_amdgcn_s_barrier();
        #pragma unroll
        for (int mr = 0; mr < 4; ++mr)
            #pragma unroll
            for (int ks = 0; ks < 2; ++ks)
                af[mr * 2 + ks] = ldsfrag(As[cur], (mr + 4) * 32 + wr16 + col, ks, quad);
        stage64(As[nxt] + 0 * 4096, A, m0 + 0,   kN, w, lane);
        stage64(As[nxt] + 1 * 4096, A, m0 + 64,  kN, w, lane);
        stage64(As[nxt] + 2 * 4096, A, m0 + 128, kN, w, lane);
        stage64(As[nxt] + 3 * 4096, A, m0 + 192, kN, w, lane);
        __builtin_amdgcn_s_setprio(1);
        #pragma unroll
        for (int mr = 0; mr < 4; ++mr)
            #pragma unroll
            for (int nt = 0; nt < 3; ++nt)
                #pragma unroll
                for (int ks = 0; ks < 2; ++ks)
                    acc[mr + 4][nt] = mfma16(af[mr * 2 + ks], bfc[nt * 2 + ks], acc[mr + 4][nt]);
        __builtin_amdgcn_s_setprio(0);
    }

    // ---- epilogue: QKV scatter (same lane->element mapping as gemm_k)
    #pragma unroll
    for (int mr = 0; mr < 8; ++mr) {
        #pragma unroll
        for (int nt = 0; nt < 3; ++nt) {
            #pragma unroll
            for (int r = 0; r < 4; ++r) {
                int gm = m0 + mr * 32 + wr16 + quad * 4 + r;
                int gn = n0 + wc48 + nt * 16 + col;
                u16 bv = f2bf(acc[mr][nt][r]);
                int b = gm >> 10, tq = gm & 1023;
                int which = gn >> 11, rem = gn & 2047;
                int hh = rem >> 7, d = rem & 127;
                size_t bh = (size_t)b * 16 + hh;
                if (which == 0)      Qo[(bh * 1024 + tq) * 128 + d] = bv;
                else if (which == 1) Ko[(bh * 1024 + tq) * 128 + d] = bv;
                else                 Vt[(bh * 128 + d) * 1024 + tq] = bv;
            }
        }
    }
}

// ---------------------------------------------------------------------------
// Flash attention R17: R8 async16 staging (reverted from R16 reg-staging) +
// q-tile pairing. Grid (8, H, B) = 512 blocks, 256 threads = 4 waves.
// Each block processes q-tiles {15-bx, bx} sequentially -> uniform 17
// K-tiles/block, one clean co-resident round (fixes R16-measured 11%
// occupancy tail). K tile [64][128] + V^T tile [128][64] staged via
// async16 with XOR-swizzle on the global source; S^T = K.Q^T scalar
// softmax; Ps wave-private; O overwrites Q in place (single-writer,
// read-before-own-write, cross-set rows disjoint).
// ---------------------------------------------------------------------------
__global__ __launch_bounds__(256) void attn_kernel(
    u16* __restrict__ Q, const u16* __restrict__ K,
    const u16* __restrict__ VT) {
    __shared__ u16 Ks[64 * 128];     // swizzled, unpadded (async16 dst)
    __shared__ u16 Vs[128 * 64];     // swizzled, unpadded
    __shared__ u16 Ps[4][16][68];    // wave-private, padded (normal ds_write)

    const int bx = (int)blockIdx.x;               // 0..7
    const int h = blockIdx.y, b = blockIdx.z;
    const int t = threadIdx.x;
    const int w = t >> 6, lane = t & 63;
    const int col = lane & 15, quad = lane >> 4;
    const int sw = col & 7;                       // read-side swizzle key
    const size_t bh = (size_t)b * 16 + h;
    u16* Qb = Q + bh * (1024 * 128);
    const u16* Kb = K + bh * (1024 * 128);
    const u16* Vb = VT + bh * (128 * 1024);
    const float scale = 0.08838834764831845f;     // 1/sqrt(128)

    #pragma unroll 1
    for (int qs = 0; qs < 2; ++qs) {
        const int qb = qs ? bx : 15 - bx;         // pair (15-bx, bx): 17 tiles
        const int q_lane = qb * 64 + w * 16 + col;

        // Q fragment, B-operand: lane holds Q[q=col][dh=kq*32+quad*8+j]
        bf16x8 qf[4];
        {
            const u16* qp = Qb + (size_t)q_lane * 128 + quad * 8;
            #pragma unroll
            for (int kq = 0; kq < 4; ++kq)
                qf[kq] = *(const bf16x8*)(qp + kq * 32);
        }

        f32x4 o[8];
        #pragma unroll
        for (int i = 0; i < 8; ++i) o[i] = (f32x4){0.f, 0.f, 0.f, 0.f};
        float m = NEG_BIG, l = 0.f;

        for (int kt = 0; kt <= qb; ++kt) {
            const u16* Kt = Kb + (size_t)kt * (64 * 128);

            // ---- stage K (64x128) + V^T (128x64) via swizzled async16 ----
            #pragma unroll
            for (int i = 0; i < 4; ++i) {
                int s = i * 256 + w * 64 + lane;      // chunk slot incl. lane
                int kr = s >> 4, kc = s & 15;         // K: 16 chunks/row
                async16(Kt + (size_t)kr * 128 + ((kc ^ (kr & 7)) << 3),
                        Ks + (size_t)(i * 256 + w * 64) * 8);
                int vr = s >> 3, vc = s & 7;          // V: 8 chunks/row
                async16(Vb + (size_t)vr * 1024 + kt * 64 + ((vc ^ (vr & 7)) << 3),
                        Vs + (size_t)(i * 256 + w * 64) * 8);
            }
            __syncthreads();

            // ---- S^T = K.Q^T ----
            const bool need_mask = (kt == qb);
            const int ttmax = need_mask ? w : 3;      // skip fully-masked strips
            f32x4 s[4];
            #pragma unroll
            for (int tt = 0; tt < 4; ++tt) {
                if (tt > ttmax) { s[tt] = (f32x4){NEG_BIG, NEG_BIG, NEG_BIG, NEG_BIG}; continue; }
                const u16* kbase = Ks + (size_t)(tt * 16 + col) * 128;
                f32x4 a = (f32x4){0.f, 0.f, 0.f, 0.f};
                #pragma unroll
                for (int kq = 0; kq < 4; ++kq)
                    a = mfma16(*(const bf16x8*)(kbase + (((kq * 4 + quad) ^ sw) << 3)),
                               qf[kq], a);
                s[tt] = a;
            }

            // ---- scale + mask + max ----
            float rmax = NEG_BIG;
            #pragma unroll
            for (int tt = 0; tt < 4; ++tt) {
                if (tt > ttmax) continue;
                #pragma unroll
                for (int r = 0; r < 4; ++r) {
                    float v = s[tt][r] * scale;
                    int tg = kt * 64 + tt * 16 + quad * 4 + r;
                    if (need_mask && tg > q_lane) v = NEG_BIG;
                    s[tt][r] = v;
                    rmax = fmaxf(rmax, v);
                }
            }
            rmax = fmaxf(rmax, __shfl_xor(rmax, 16, 64));
            rmax = fmaxf(rmax, __shfl_xor(rmax, 32, 64));

            float mnew = fmaxf(m, rmax);
            float alpha = __expf(m - mnew);
            m = mnew;

            // ---- P = exp(S^T - m) -> Ps[w][q][t] ----
            float rsum = 0.f;
            #pragma unroll
            for (int tt = 0; tt < 4; ++tt) {
                uint32_t* dst = (uint32_t*)&Ps[w][col][tt * 16 + quad * 4];
                if (tt > ttmax) { dst[0] = 0u; dst[1] = 0u; continue; }
                float p0 = __expf(s[tt][0] - mnew);
                float p1 = __expf(s[tt][1] - mnew);
                float p2 = __expf(s[tt][2] - mnew);
                float p3 = __expf(s[tt][3] - mnew);
                rsum += (p0 + p1) + (p2 + p3);
                dst[0] = pack2(p0, p1);
                dst[1] = pack2(p2, p3);
            }
            rsum += __shfl_xor(rsum, 16, 64);
            rsum += __shfl_xor(rsum, 32, 64);
            l = l * alpha + rsum;

            #pragma unroll
            for (int dt = 0; dt < 8; ++dt)
                #pragma unroll
                for (int r = 0; r < 4; ++r) o[dt][r] *= alpha;

            // ---- O^T += V^T.P^T ----
            #pragma unroll
            for (int ks = 0; ks < 2; ++ks) {
                bf16x8 pf = *(const bf16x8*)&Ps[w][col][ks * 32 + quad * 8];
                #pragma unroll
                for (int dt = 0; dt < 8; ++dt) {
                    const u16* vbase = Vs + (size_t)(dt * 16 + col) * 64;
                    o[dt] = mfma16(*(const bf16x8*)(vbase + (((ks * 4 + quad) ^ sw) << 3)),
                                   pf, o[dt]);
                }
            }
            __syncthreads();   // all waves done reading before next overwrite
        }

        // epilogue: lane holds O^T[d=dt*16+quad*4+r][q=col]; 8B packed stores
        float inv = 1.0f / l;
        #pragma unroll
        for (int dt = 0; dt < 8; ++dt) {
            uint2 p;
            p.x = pack2(o[dt][0] * inv, o[dt][1] * inv);
            p.y = pack2(o[dt][2] * inv, o[dt][3] * inv);
            *(uint2*)&Qb[(size_t)q_lane * 128 + dt * 16 + quad * 4] = p;
        }
    }
}

// ---------------------------------------------------------------------------
extern "C" void kernel_launch(void* const* d_in, const int* in_sizes, int n_in,
                              void* d_out, int out_size, void* d_ws, size_t ws_size,
                              hipStream_t stream) {
    const float* x      = (const float*)d_in[0];   // [4096, 2048]
    const float* w_qkv  = (const float*)d_in[1];   // [2048, 6144]
    const float* w_proj = (const float*)d_in[2];   // [2048, 2048]
    float* out = (float*)d_out;                    // [4096, 2048]

    const size_t SEG = (size_t)4 * 16 * 1024 * 128;      // 8,388,608 elems
    const size_t NEED_FAST = ((size_t)6144 * 2048 + SEG * 4) * 2;  // 92.3 MB

    if (ws_size >= NEED_FAST + (1u << 20)) {
        u16* wT = (u16*)d_ws;                 // 6144*2048, reused for proj
        u16* xb = wT + (size_t)6144 * 2048;
        u16* Qb = xb + SEG;
        u16* Kb = Qb + SEG;
        u16* Vb = Kb + SEG;

        cvt_bf16<<<4096, 256, 0, stream>>>(x, xb);
        transpose_w<<<dim3(96, 32), 256, 0, stream>>>(w_qkv, 6144, wT);

        gemm192<<<dim3(32, 16), 512, 0, stream>>>(xb, wT, Qb, Kb, Vb);

        attn_kernel<<<dim3(8, 16, 4), 256, 0, stream>>>(Qb, Kb, Vb);

        transpose_w<<<dim3(32, 32), 256, 0, stream>>>(w_proj, 2048, wT);
        gemm_k<<<dim3(16, 32), 256, 0, stream>>>(Qb, wT, 2048, 1, 0,
                                                 out, nullptr, nullptr, nullptr);
    } else {
        // fallback (ws >= 58.7 MB), R5-proven sequence
        u16* wT = (u16*)d_ws;
        u16* Qb = wT + (size_t)2048 * 2048;
        u16* Kb = Qb + SEG;
        u16* Vb = Kb + SEG;

        transpose_w<<<dim3(32, 32), 256, 0, stream>>>(w_qkv + 0, 6144, wT);
        gemm_k<<<dim3(16, 32), 256, 0, stream>>>(x, wT, 2048, 0, 1,
                                                 nullptr, Qb, nullptr, nullptr);
        transpose_w<<<dim3(32, 32), 256, 0, stream>>>(w_qkv + 2048, 6144, wT);
        gemm_k<<<dim3(16, 32), 256, 0, stream>>>(x, wT, 2048, 0, 1,
                                                 nullptr, Kb, nullptr, nullptr);
        transpose_w<<<dim3(32, 32), 256, 0, stream>>>(w_qkv + 4096, 6144, wT);
        gemm_k<<<dim3(16, 32), 256, 0, stream>>>(x, wT, 2048, 0, 2,
                                                 nullptr, nullptr, nullptr, Vb);

        attn_kernel<<<dim3(8, 16, 4), 256, 0, stream>>>(Qb, Kb, Vb);

        transpose_w<<<dim3(32, 32), 256, 0, stream>>>(w_proj, 2048, wT);
        gemm_k<<<dim3(16, 32), 256, 0, stream>>>(Qb, wT, 2048, 3, 0,
                                                 out, nullptr, nullptr, nullptr);
    }
}